// Round 7
// baseline (69.697 us; speedup 1.0000x reference)
//
#include <hip/hip_runtime.h>
#include <hip/hip_bf16.h>

// Problem constants: B=16384, N=20, D=64, R=3, K=64
#define BB   16384
#define NN   20
#define NREL 3

typedef __attribute__((ext_vector_type(8))) short  short8;
typedef __attribute__((ext_vector_type(4))) float  f32x4;

__device__ __forceinline__ float lo16(unsigned int u) {
    union { unsigned int x; float f; } c; c.x = u << 16; return c.f;
}
__device__ __forceinline__ float hi16(unsigned int u) {
    union { unsigned int x; float f; } c; c.x = u & 0xFFFF0000u; return c.f;
}

// f32 -> bf16 (RNE), returned as raw ushort
__device__ __forceinline__ unsigned short f2bu(float f) {
    union { float f; unsigned int u; } x;
    x.f = f;
    unsigned int r = x.u + 0x7FFFu + ((x.u >> 16) & 1u);
    return (unsigned short)(r >> 16);
}

// ---------------------------------------------------------------------------
// K1: McatT[r*128+e][d] = sum_k w_uir[r][d][k] * w_aor[r][e][k]   (bf16 out)
//     cvec[r*128+e]     = sum_k r_vec[r][k]   * w_aor[r][e][k]    (f32 out)
// ---------------------------------------------------------------------------
__global__ __launch_bounds__(256) void k_precompute(
    const float* __restrict__ w_uir,
    const float* __restrict__ w_aor,
    const float* __restrict__ r_vec,
    unsigned short* __restrict__ McatT,   // [384][128] bf16 bits
    float* __restrict__ cvec)             // [384]
{
    int idx = blockIdx.x * 256 + threadIdx.x;
    if (idx < NREL * 128 * 128) {
        int d = idx & 127;
        int e = (idx >> 7) & 127;
        int r = idx >> 14;
        const float4* pu = reinterpret_cast<const float4*>(w_uir + (r * 128 + d) * 64);
        const float4* pa = reinterpret_cast<const float4*>(w_aor + (r * 128 + e) * 64);
        float acc = 0.f;
        #pragma unroll
        for (int k = 0; k < 16; ++k) {
            float4 a = pu[k], b = pa[k];
            acc += a.x * b.x + a.y * b.y + a.z * b.z + a.w * b.w;
        }
        McatT[(r * 128 + e) * 128 + d] = f2bu(acc);
    } else if (idx < NREL * 128 * 128 + NREL * 128) {
        int j = idx - NREL * 128 * 128;
        int r = j >> 7, e = j & 127;
        const float4* pr = reinterpret_cast<const float4*>(r_vec + r * 64);
        const float4* pa = reinterpret_cast<const float4*>(w_aor + (r * 128 + e) * 64);
        float acc = 0.f;
        #pragma unroll
        for (int k = 0; k < 16; ++k) {
            float4 a = pr[k], b = pa[k];
            acc += a.x * b.x + a.y * b.y + a.z * b.z + a.w * b.w;
        }
        cvec[j] = acc;
    }
}

// ---------------------------------------------------------------------------
// K2: v'[b][j] = sum_d ui_in[b][d] * McatT[j][d] + cvec[j]
//     GEMM M=16384 N=384 K=128, bf16 MFMA 16x16x32, 64x64 block tiles.
// ---------------------------------------------------------------------------
__global__ __launch_bounds__(256) void k_gemm(
    const float* __restrict__ u_emb,
    const float* __restrict__ i_emb,
    const unsigned short* __restrict__ McatT,  // [384][128] bf16 bits
    const float* __restrict__ cvec,            // [384]
    unsigned short* __restrict__ vp)           // [16384][384] bf16 bits
{
    __shared__ unsigned short Atile[64][136];  // +8 pad
    const int t = threadIdx.x;
    const int bm = blockIdx.x & 255;   // 256 M tiles
    const int bn = blockIdx.x >> 8;    // 6 N tiles
    const int Mbase = bm * 64;
    const int Nbase = bn * 64;

    #pragma unroll
    for (int it = 0; it < 8; ++it) {
        int idx  = it * 256 + t;       // 0..2047, each covers 4 floats
        int row  = idx >> 5;
        int colg = idx & 31;
        const float* src = (colg < 16)
            ? (u_emb + (Mbase + row) * 64 + colg * 4)
            : (i_emb + (Mbase + row) * 64 + (colg - 16) * 4);
        float4 v = *reinterpret_cast<const float4*>(src);
        ushort4 h;
        h.x = f2bu(v.x); h.y = f2bu(v.y); h.z = f2bu(v.z); h.w = f2bu(v.w);
        *reinterpret_cast<ushort4*>(&Atile[row][colg * 4]) = h;
    }
    __syncthreads();

    const int w    = t >> 6;
    const int lane = t & 63;
    const int lr   = lane & 15;
    const int lk   = (lane >> 4) * 8;

    short8 afrag[4];
    #pragma unroll
    for (int kk = 0; kk < 4; ++kk)
        afrag[kk] = *reinterpret_cast<const short8*>(&Atile[w * 16 + lr][kk * 32 + lk]);

    #pragma unroll
    for (int nt = 0; nt < 4; ++nt) {
        f32x4 acc = {0.f, 0.f, 0.f, 0.f};
        int col = Nbase + nt * 16 + lr;
        #pragma unroll
        for (int kk = 0; kk < 4; ++kk) {
            short8 bfrag = *reinterpret_cast<const short8*>(McatT + col * 128 + kk * 32 + lk);
            acc = __builtin_amdgcn_mfma_f32_16x16x32_bf16(afrag[kk], bfrag, acc, 0, 0, 0);
        }
        float cb = cvec[col];
        #pragma unroll
        for (int reg = 0; reg < 4; ++reg) {
            int grow = Mbase + w * 16 + (lane >> 4) * 4 + reg;
            vp[grow * 384 + col] = f2bu(acc[reg] + cb);
        }
    }
}

// ---------------------------------------------------------------------------
// K3: pred[t] = sum_e ao_in[t][e] * v'[b][s[t]*128 + e],  ao_in = [a|o]
//     4 lanes per triple: lane q owns a 64B quarter of the a-row, o-row and
//     vp-row. 2 triples per thread = 24 mutually-independent b128 loads in
//     one straight-line basic block (no loops, no cross-iteration state for
//     regalloc to destroy). Every load instruction is wave-dense (4KB
//     contiguous). Quad shfl_xor reduce, lane q==0 stores.
// ---------------------------------------------------------------------------
#define K3_BLOCKS 2560
#define K3_HALF   163840     // triples covered by first thread sweep

__global__ __launch_bounds__(256) void k_pred(
    const float* __restrict__ a_emb,
    const float* __restrict__ o_emb,
    const int* __restrict__ s,
    const unsigned short* __restrict__ vp,
    float* __restrict__ out)
{
    const int g  = blockIdx.x * 256 + threadIdx.x;   // 0..655359
    const int q  = g & 3;                            // quad lane
    const int t0 = g >> 2;                           // triple 0..163839
    const int t1 = t0 + K3_HALF;

    // s loads first (vp addresses depend on them)
    const int s0 = s[t0];
    const int s1 = s[t1];

    // a/o loads: independent of s -> issue fills the s->vp latency window
    const float4* pa0 = (const float4*)(a_emb + (size_t)t0 * 64 + q * 16);
    const float4* po0 = (const float4*)(o_emb + (size_t)t0 * 64 + q * 16);
    const float4* pa1 = (const float4*)(a_emb + (size_t)t1 * 64 + q * 16);
    const float4* po1 = (const float4*)(o_emb + (size_t)t1 * 64 + q * 16);

    float4 a00 = pa0[0], a01 = pa0[1], a02 = pa0[2], a03 = pa0[3];
    float4 o00 = po0[0], o01 = po0[1], o02 = po0[2], o03 = po0[3];
    float4 a10 = pa1[0], a11 = pa1[1], a12 = pa1[2], a13 = pa1[3];
    float4 o10 = po1[0], o11 = po1[1], o12 = po1[2], o13 = po1[3];

    // vp rows: [b*3 + s] * 128 bf16; lane q owns bf16 [q*16, q*16+16) of the
    // a-half and the same slice of the o-half (+64).
    const unsigned short* vb0 = vp + (((size_t)(t0 / NN) * 3 + s0) << 7);
    const unsigned short* vb1 = vp + (((size_t)(t1 / NN) * 3 + s1) << 7);
    const uint4* pv0a = (const uint4*)(vb0 + q * 16);
    const uint4* pv0o = (const uint4*)(vb0 + 64 + q * 16);
    const uint4* pv1a = (const uint4*)(vb1 + q * 16);
    const uint4* pv1o = (const uint4*)(vb1 + 64 + q * 16);

    uint4 w0a0 = pv0a[0], w0a1 = pv0a[1];
    uint4 w0o0 = pv0o[0], w0o1 = pv0o[1];
    uint4 w1a0 = pv1a[0], w1a1 = pv1a[1];
    uint4 w1o0 = pv1o[0], w1o1 = pv1o[1];

    // 16-float x 16-bf16 quarter-row dot
    #define DOTQ(A0, A1, A2, A3, W0, W1) ( \
        (A0).x * lo16((W0).x) + (A0).y * hi16((W0).x) + \
        (A0).z * lo16((W0).y) + (A0).w * hi16((W0).y) + \
        (A1).x * lo16((W0).z) + (A1).y * hi16((W0).z) + \
        (A1).z * lo16((W0).w) + (A1).w * hi16((W0).w) + \
        (A2).x * lo16((W1).x) + (A2).y * hi16((W1).x) + \
        (A2).z * lo16((W1).y) + (A2).w * hi16((W1).y) + \
        (A3).x * lo16((W1).z) + (A3).y * hi16((W1).z) + \
        (A3).z * lo16((W1).w) + (A3).w * hi16((W1).w) )

    float r0 = DOTQ(a00, a01, a02, a03, w0a0, w0a1)
             + DOTQ(o00, o01, o02, o03, w0o0, w0o1);
    float r1 = DOTQ(a10, a11, a12, a13, w1a0, w1a1)
             + DOTQ(o10, o11, o12, o13, w1o0, w1o1);
    #undef DOTQ

    // quad reduce
    r0 += __shfl_xor(r0, 1, 64);
    r0 += __shfl_xor(r0, 2, 64);
    r1 += __shfl_xor(r1, 1, 64);
    r1 += __shfl_xor(r1, 2, 64);

    if (q == 0) {
        out[t0] = r0;
        out[t1] = r1;
    }
}

// ---------------------------------------------------------------------------
extern "C" void kernel_launch(void* const* d_in, const int* in_sizes, int n_in,
                              void* d_out, int out_size, void* d_ws, size_t ws_size,
                              hipStream_t stream) {
    const float* u_emb = (const float*)d_in[0];
    const float* i_emb = (const float*)d_in[1];
    const float* a_emb = (const float*)d_in[2];
    const float* o_emb = (const float*)d_in[3];
    const int*   s     = (const int*)d_in[4];
    const float* w_uir = (const float*)d_in[5];
    const float* w_aor = (const float*)d_in[6];
    const float* r_vec = (const float*)d_in[7];
    float* out = (float*)d_out;

    char* ws = (char*)d_ws;
    unsigned short* McatT = (unsigned short*)ws;              // 98304 B
    float*          cvec  = (float*)(ws + 98304);             // 1536 B
    unsigned short* vp    = (unsigned short*)(ws + 102400);   // 12.58 MB

    k_precompute<<<194, 256, 0, stream>>>(w_uir, w_aor, r_vec, McatT, cvec);
    k_gemm<<<1536, 256, 0, stream>>>(u_emb, i_emb, McatT, cvec, vp);
    k_pred<<<K3_BLOCKS, 256, 0, stream>>>(a_emb, o_emb, s, vp, out);
}

// Round 8
// 53.243 us; speedup vs baseline: 1.3090x; 1.3090x over previous
//
#include <hip/hip_runtime.h>
#include <hip/hip_bf16.h>

// Problem constants: B=16384, N=20, D=64, R=3, K=64
#define BB   16384
#define NN   20
#define NREL 3

typedef __attribute__((ext_vector_type(8))) short  short8;
typedef __attribute__((ext_vector_type(4))) float  f32x4;

__device__ __forceinline__ float lo16(unsigned int u) {
    union { unsigned int x; float f; } c; c.x = u << 16; return c.f;
}
__device__ __forceinline__ float hi16(unsigned int u) {
    union { unsigned int x; float f; } c; c.x = u & 0xFFFF0000u; return c.f;
}

// f32 -> bf16 (RNE), returned as raw ushort
__device__ __forceinline__ unsigned short f2bu(float f) {
    union { float f; unsigned int u; } x;
    x.f = f;
    unsigned int r = x.u + 0x7FFFu + ((x.u >> 16) & 1u);
    return (unsigned short)(r >> 16);
}

// ---------------------------------------------------------------------------
// K1: McatT[r*128+e][d] = sum_k w_uir[r][d][k] * w_aor[r][e][k]   (bf16 out)
//     cvec[r*128+e]     = sum_k r_vec[r][k]   * w_aor[r][e][k]    (f32 out)
// ---------------------------------------------------------------------------
__global__ __launch_bounds__(256) void k_precompute(
    const float* __restrict__ w_uir,
    const float* __restrict__ w_aor,
    const float* __restrict__ r_vec,
    unsigned short* __restrict__ McatT,   // [384][128] bf16 bits
    float* __restrict__ cvec)             // [384]
{
    int idx = blockIdx.x * 256 + threadIdx.x;
    if (idx < NREL * 128 * 128) {
        int d = idx & 127;
        int e = (idx >> 7) & 127;
        int r = idx >> 14;
        const float4* pu = reinterpret_cast<const float4*>(w_uir + (r * 128 + d) * 64);
        const float4* pa = reinterpret_cast<const float4*>(w_aor + (r * 128 + e) * 64);
        float acc = 0.f;
        #pragma unroll
        for (int k = 0; k < 16; ++k) {
            float4 a = pu[k], b = pa[k];
            acc += a.x * b.x + a.y * b.y + a.z * b.z + a.w * b.w;
        }
        McatT[(r * 128 + e) * 128 + d] = f2bu(acc);
    } else if (idx < NREL * 128 * 128 + NREL * 128) {
        int j = idx - NREL * 128 * 128;
        int r = j >> 7, e = j & 127;
        const float4* pr = reinterpret_cast<const float4*>(r_vec + r * 64);
        const float4* pa = reinterpret_cast<const float4*>(w_aor + (r * 128 + e) * 64);
        float acc = 0.f;
        #pragma unroll
        for (int k = 0; k < 16; ++k) {
            float4 a = pr[k], b = pa[k];
            acc += a.x * b.x + a.y * b.y + a.z * b.z + a.w * b.w;
        }
        cvec[j] = acc;
    }
}

// ---------------------------------------------------------------------------
// K2: v'[b][j] = sum_d ui_in[b][d] * McatT[j][d] + cvec[j]
//     GEMM M=16384 N=384 K=128, bf16 MFMA 16x16x32, 64x64 block tiles.
// ---------------------------------------------------------------------------
__global__ __launch_bounds__(256) void k_gemm(
    const float* __restrict__ u_emb,
    const float* __restrict__ i_emb,
    const unsigned short* __restrict__ McatT,  // [384][128] bf16 bits
    const float* __restrict__ cvec,            // [384]
    unsigned short* __restrict__ vp)           // [16384][384] bf16 bits
{
    __shared__ unsigned short Atile[64][136];  // +8 pad
    const int t = threadIdx.x;
    const int bm = blockIdx.x & 255;   // 256 M tiles
    const int bn = blockIdx.x >> 8;    // 6 N tiles
    const int Mbase = bm * 64;
    const int Nbase = bn * 64;

    #pragma unroll
    for (int it = 0; it < 8; ++it) {
        int idx  = it * 256 + t;       // 0..2047, each covers 4 floats
        int row  = idx >> 5;
        int colg = idx & 31;
        const float* src = (colg < 16)
            ? (u_emb + (Mbase + row) * 64 + colg * 4)
            : (i_emb + (Mbase + row) * 64 + (colg - 16) * 4);
        float4 v = *reinterpret_cast<const float4*>(src);
        ushort4 h;
        h.x = f2bu(v.x); h.y = f2bu(v.y); h.z = f2bu(v.z); h.w = f2bu(v.w);
        *reinterpret_cast<ushort4*>(&Atile[row][colg * 4]) = h;
    }
    __syncthreads();

    const int w    = t >> 6;
    const int lane = t & 63;
    const int lr   = lane & 15;
    const int lk   = (lane >> 4) * 8;

    short8 afrag[4];
    #pragma unroll
    for (int kk = 0; kk < 4; ++kk)
        afrag[kk] = *reinterpret_cast<const short8*>(&Atile[w * 16 + lr][kk * 32 + lk]);

    #pragma unroll
    for (int nt = 0; nt < 4; ++nt) {
        f32x4 acc = {0.f, 0.f, 0.f, 0.f};
        int col = Nbase + nt * 16 + lr;
        #pragma unroll
        for (int kk = 0; kk < 4; ++kk) {
            short8 bfrag = *reinterpret_cast<const short8*>(McatT + col * 128 + kk * 32 + lk);
            acc = __builtin_amdgcn_mfma_f32_16x16x32_bf16(afrag[kk], bfrag, acc, 0, 0, 0);
        }
        float cb = cvec[col];
        #pragma unroll
        for (int reg = 0; reg < 4; ++reg) {
            int grow = Mbase + w * 16 + (lane >> 4) * 4 + reg;
            vp[grow * 384 + col] = f2bu(acc[reg] + cb);
        }
    }
}

// ---------------------------------------------------------------------------
// K3: pred[t] = sum_e ao_in[t][e] * v'[b][s[t]*128 + e],  ao_in = [a|o]
//     ALL bulk traffic staged via global_load_lds (register-free, deep
//     vmcnt stacking -- the proven 6TB/s GEMM staging path). Block owns
//     4 b's = 80 triples: a 20KB + o 20KB + vp 3KB = 43KB LDS, staged as
//     43 contiguous-1KB wave instructions. 3 blocks/CU co-resident overlap
//     stage/consume. Consume: 16-lane groups, XOR-swizzled sub-lanes to
//     break the 256B-row bank aliasing; only per-lane global loads left
//     are the 5 s values.
// ---------------------------------------------------------------------------
#define K3_G      4                    // b's per block
#define K3_TPB    (K3_G * NN)          // 80 triples per block
#define K3_BLOCKS (BB / K3_G)          // 4096 blocks

#define LDS_A   0
#define LDS_O   20480
#define LDS_VP  40960
#define LDS_SZ  44032

__global__ __launch_bounds__(256) void k_pred(
    const float* __restrict__ a_emb,
    const float* __restrict__ o_emb,
    const int* __restrict__ s,
    const unsigned short* __restrict__ vp,
    float* __restrict__ out)
{
    __shared__ __align__(16) char lds[LDS_SZ];

    const int tid  = threadIdx.x;
    const int bid  = blockIdx.x;
    const int wv   = tid >> 6;
    const int lane = tid & 63;

    const size_t t0 = (size_t)bid * K3_TPB;

    // per-thread consume geometry (also used for s prefetch)
    const int g   = tid >> 4;                 // group 0..15 (16 lanes each)
    const int sub = tid & 15;
    const int e4  = sub ^ (((lane >> 4) & 3) << 2);  // swizzled quarter idx

    // ---- s prefetch: the only per-lane global loads (independent, early)
    const int sv0 = s[t0 +  0 + g];
    const int sv1 = s[t0 + 16 + g];
    const int sv2 = s[t0 + 32 + g];
    const int sv3 = s[t0 + 48 + g];
    const int sv4 = s[t0 + 64 + g];

    // ---- stage a (20 segs), o (20 segs), vp (3 segs); seg = 1KB
    {
        const char* asrc = (const char*)(a_emb + t0 * 64);
        const char* osrc = (const char*)(o_emb + t0 * 64);
        const char* vsrc = (const char*)(vp + (size_t)bid * (K3_G * 3 * 128));
        #pragma unroll
        for (int i = 0; i < 5; ++i) {
            int seg = i * 4 + wv;
            __builtin_amdgcn_global_load_lds(
                (const unsigned int*)(asrc + seg * 1024 + lane * 16),
                (unsigned int*)(lds + LDS_A + seg * 1024), 16, 0, 0);
        }
        #pragma unroll
        for (int i = 0; i < 5; ++i) {
            int seg = i * 4 + wv;
            __builtin_amdgcn_global_load_lds(
                (const unsigned int*)(osrc + seg * 1024 + lane * 16),
                (unsigned int*)(lds + LDS_O + seg * 1024), 16, 0, 0);
        }
        if (wv < 3) {
            __builtin_amdgcn_global_load_lds(
                (const unsigned int*)(vsrc + wv * 1024 + lane * 16),
                (unsigned int*)(lds + LDS_VP + wv * 1024), 16, 0, 0);
        }
    }
    asm volatile("s_waitcnt vmcnt(0)");
    __syncthreads();

    // ---- consume: 5 passes x 16 triples; lane owns floats [e4*4, e4*4+4)
    #define PASS(P, SV)                                                        \
    {                                                                          \
        const int ltrip = (P) * 16 + g;                                        \
        const int bl    = ltrip / NN;                                          \
        const int row   = bl * 3 + (SV);                                       \
        float4 af = *(const float4*)(lds + LDS_A + ltrip * 256 + e4 * 16);     \
        float4 of = *(const float4*)(lds + LDS_O + ltrip * 256 + e4 * 16);     \
        uint2  wa = *(const uint2*)(lds + LDS_VP + row * 256 + e4 * 8);        \
        uint2  wo = *(const uint2*)(lds + LDS_VP + row * 256 + 128 + e4 * 8);  \
        float r = af.x * lo16(wa.x) + af.y * hi16(wa.x)                        \
                + af.z * lo16(wa.y) + af.w * hi16(wa.y)                        \
                + of.x * lo16(wo.x) + of.y * hi16(wo.x)                        \
                + of.z * lo16(wo.y) + of.w * hi16(wo.y);                       \
        r += __shfl_xor(r, 1, 64);                                             \
        r += __shfl_xor(r, 2, 64);                                             \
        r += __shfl_xor(r, 4, 64);                                             \
        r += __shfl_xor(r, 8, 64);                                             \
        if (sub == 0) out[t0 + ltrip] = r;                                     \
    }

    PASS(0, sv0)
    PASS(1, sv1)
    PASS(2, sv2)
    PASS(3, sv3)
    PASS(4, sv4)
    #undef PASS
}

// ---------------------------------------------------------------------------
extern "C" void kernel_launch(void* const* d_in, const int* in_sizes, int n_in,
                              void* d_out, int out_size, void* d_ws, size_t ws_size,
                              hipStream_t stream) {
    const float* u_emb = (const float*)d_in[0];
    const float* i_emb = (const float*)d_in[1];
    const float* a_emb = (const float*)d_in[2];
    const float* o_emb = (const float*)d_in[3];
    const int*   s     = (const int*)d_in[4];
    const float* w_uir = (const float*)d_in[5];
    const float* w_aor = (const float*)d_in[6];
    const float* r_vec = (const float*)d_in[7];
    float* out = (float*)d_out;

    char* ws = (char*)d_ws;
    unsigned short* McatT = (unsigned short*)ws;              // 98304 B
    float*          cvec  = (float*)(ws + 98304);             // 1536 B
    unsigned short* vp    = (unsigned short*)(ws + 102400);   // 12.58 MB

    k_precompute<<<194, 256, 0, stream>>>(w_uir, w_aor, r_vec, McatT, cvec);
    k_gemm<<<1536, 256, 0, stream>>>(u_emb, i_emb, McatT, cvec, vp);
    k_pred<<<K3_BLOCKS, 256, 0, stream>>>(a_emb, o_emb, s, vp, out);
}